// Round 7
// baseline (1265.902 us; speedup 1.0000x reference)
//
#include <hip/hip_runtime.h>
#include <stdint.h>

typedef unsigned short u16;
typedef unsigned int u32;
typedef __attribute__((ext_vector_type(8))) short short8;
typedef __attribute__((ext_vector_type(4))) float floatx4;

#define NB 1024  // grid size; co-resident at 4 blocks/CU x 256 CUs

__device__ __forceinline__ u16 f2b(float f) {
    u32 u = __builtin_bit_cast(u32, f);
    return (u16)((u + 0x7fffu + ((u >> 16) & 1u)) >> 16);
}
__device__ __forceinline__ float b2f(u16 b) {
    u32 u = ((u32)b) << 16;
    return __builtin_bit_cast(float, u);
}
__device__ __forceinline__ void gld16(const void* g, void* l) {
    __builtin_amdgcn_global_load_lds(
        (const __attribute__((address_space(1))) u32*)g,
        (__attribute__((address_space(3))) u32*)l, 16, 0, 0);
}

// device-scope grid barrier (cooperative-groups protocol, all NB blocks resident)
__device__ __forceinline__ void gbar(u32* cnt, u32* gen) {
    __syncthreads();
    if (threadIdx.x == 0) {
        __threadfence();  // release all prior global writes (agent scope, cross-XCD)
        u32 g = __hip_atomic_load(gen, __ATOMIC_RELAXED, __HIP_MEMORY_SCOPE_AGENT);
        u32 a = __hip_atomic_fetch_add(cnt, 1u, __ATOMIC_ACQ_REL, __HIP_MEMORY_SCOPE_AGENT);
        if (a == NB - 1) {
            __hip_atomic_store(cnt, 0u, __ATOMIC_RELAXED, __HIP_MEMORY_SCOPE_AGENT);
            __hip_atomic_fetch_add(gen, 1u, __ATOMIC_ACQ_REL, __HIP_MEMORY_SCOPE_AGENT);
        } else {
            while (__hip_atomic_load(gen, __ATOMIC_ACQUIRE, __HIP_MEMORY_SCOPE_AGENT) == g)
                __builtin_amdgcn_s_sleep(8);
        }
        __threadfence();  // acquire side
    }
    __syncthreads();
}

// 64(M)x128(N) tile GEMM body, BK=64, 256 thr (2x2 waves of 32x64).
// XOR-swizzled LDS, conflict-free ds_read_b128. Ap/Bp pre-offset to tile+kOff.
// Cp!=null -> bf16 store (pre-offset); else fp32 C with rowscale.
__device__ __forceinline__ void gemm_body(
    const u16* Ap, const u16* Bp, u16* As, u16* Bs,
    float* C, u16* Cp, const float* __restrict__ rowscale,
    int lda, int ldb, int ldc, int m0base, int n0base, int kIters) {
    int t = threadIdx.x;
    int lane = t & 63, w = t >> 6;
    int wm = (w & 1) * 32, wn = (w >> 1) * 64;
    int r16 = lane & 15, q = lane >> 4;

    int acl[2], bcl[4];
    #pragma unroll
    for (int j = 0; j < 2; j++) acl[j] = (w * 2 + j) * 64 + lane;
    #pragma unroll
    for (int j = 0; j < 4; j++) bcl[j] = (w * 4 + j) * 64 + lane;

    floatx4 acc[2][4];
    #pragma unroll
    for (int i = 0; i < 2; i++)
        #pragma unroll
        for (int j = 0; j < 4; j++) acc[i][j] = (floatx4){0.f, 0.f, 0.f, 0.f};

    for (int kt = 0; kt < kIters; kt++) {
        long kk = (long)kt * 64;
        #pragma unroll
        for (int j = 0; j < 2; j++) {
            int cl = acl[j], row = cl >> 3, cg = (cl & 7) ^ (row & 7);
            gld16(Ap + (long)row * lda + kk + cg * 8, (void*)&As[cl * 8]);
        }
        #pragma unroll
        for (int j = 0; j < 4; j++) {
            int cl = bcl[j], row = cl >> 3, cg = (cl & 7) ^ (row & 7);
            gld16(Bp + (long)row * ldb + kk + cg * 8, (void*)&Bs[cl * 8]);
        }
        __syncthreads();
        #pragma unroll
        for (int ks = 0; ks < 2; ks++) {
            short8 a[2], b[4];
            #pragma unroll
            for (int i = 0; i < 2; i++) {
                int rr = wm + i * 16 + r16;
                int cc = (ks * 4 + q) ^ (rr & 7);
                a[i] = *(const short8*)&As[rr * 64 + cc * 8];
            }
            #pragma unroll
            for (int j = 0; j < 4; j++) {
                int rr = wn + j * 16 + r16;
                int cc = (ks * 4 + q) ^ (rr & 7);
                b[j] = *(const short8*)&Bs[rr * 64 + cc * 8];
            }
            #pragma unroll
            for (int i = 0; i < 2; i++)
                #pragma unroll
                for (int j = 0; j < 4; j++)
                    acc[i][j] = __builtin_amdgcn_mfma_f32_16x16x32_bf16(a[i], b[j], acc[i][j], 0, 0, 0);
        }
        __syncthreads();
    }

    int m0 = m0base + wm, n0 = n0base + wn;
    #pragma unroll
    for (int i = 0; i < 2; i++) {
        int mm = m0 + i * 16 + q * 4;
        float rs[4];
        #pragma unroll
        for (int r = 0; r < 4; r++) rs[r] = (rowscale != nullptr) ? rowscale[mm + r] : 1.0f;
        #pragma unroll
        for (int j = 0; j < 4; j++) {
            int nn = n0 + j * 16 + r16;
            #pragma unroll
            for (int r = 0; r < 4; r++) {
                long idx = (long)(mm + r) * ldc + nn;
                if (Cp != nullptr) Cp[idx] = f2b(acc[i][j][r]);
                else               C[idx] = acc[i][j][r] * rs[r];
            }
        }
    }
}

__global__ __launch_bounds__(256, 4) void fused_gcn(
    const float* __restrict__ x, const float* __restrict__ wgt,
    float* __restrict__ out, char* __restrict__ ws) {
    __shared__ __align__(16) char smem[24576];
    u16* As = (u16*)smem;
    u16* Bs = (u16*)(smem + 8192);

    u32* cnt = (u32*)ws;
    u32* gen = (u32*)(ws + 64);
    const size_t MB = 1048576;
    float* rnorm  = (float*)(ws + 4096);
    float* srnorm = (float*)(ws + 36864);
    char*  base   = ws + 65536 + 4096;
    u16* xb = (u16*)base;                  // 16 MB bf16(x) [8192][1024]
    u16* YT = (u16*)(base + 16 * MB);      // 16 MB Y^T [1024][8192]
    u16* Wt = (u16*)(base + 32 * MB);      //  2 MB W^T
    u16* Gb = (u16*)(base + 34 * MB);      //  2 MB G bf16
    u16* Mt = (u16*)(base + 36 * MB);      //  2 MB M^T bf16
    u16* Gp = (u16*)(base + 38 * MB);      // 16 MB 8 bf16 G-partial slabs
    u16* Mp = (u16*)(base + 54 * MB);      //  8 MB 4 bf16 M-partial slabs

    int bid = blockIdx.x;
    int t = threadIdx.x;
    int lane = t & 63, w = t >> 6;

    // ---- Phase A: row norms + xb = bf16(x). 8 rows/block, 2 rows/wave ----
    #pragma unroll
    for (int rr = 0; rr < 2; rr++) {
        int row = bid * 8 + w * 2 + rr;
        const float4* xr = (const float4*)(x + (long)row * 1024);
        float4 v[4];
        float ss = 0.f;
        #pragma unroll
        for (int j = 0; j < 4; j++) {
            v[j] = xr[lane + 64 * j];
            ss += v[j].x * v[j].x + v[j].y * v[j].y + v[j].z * v[j].z + v[j].w * v[j].w;
        }
        #pragma unroll
        for (int off = 1; off < 64; off <<= 1) ss += __shfl_xor(ss, off);
        float r = 1.0f / fmaxf(sqrtf(ss), 1e-12f);
        if (lane == 0) { rnorm[row] = r; srnorm[row] = sqrtf(r); }
        #pragma unroll
        for (int j = 0; j < 4; j++) {
            ushort4 o;
            o.x = f2b(v[j].x); o.y = f2b(v[j].y); o.z = f2b(v[j].z); o.w = f2b(v[j].w);
            *(ushort4*)(xb + (long)row * 1024 + (lane + 64 * j) * 4) = o;
        }
    }
    gbar(cnt, gen);

    // ---- Phase B: YT from xb (jobs 0..2047) + Wt from wgt (jobs 2048..2303) ----
    for (int job = bid; job < 2304; job += NB) {
        __syncthreads();  // protect smem reuse
        if (job < 2048) {
            u16 (*tile)[72] = (u16(*)[72])smem;
            float* rb = (float*)(smem + 64 * 72 * 2);
            int r0 = (job >> 4) * 64, c0 = (job & 15) * 64;
            if (t < 64) rb[t] = srnorm[r0 + t];
            __syncthreads();
            #pragma unroll
            for (int i = 0; i < 4; i++) {
                int lin = i * 256 + t;
                int rr = lin >> 4, c4 = (lin & 15) << 2;
                ushort4 v = *(const ushort4*)(xb + (long)(r0 + rr) * 1024 + c0 + c4);
                float s = rb[rr];
                tile[rr][c4]     = f2b(b2f(v.x) * s);
                tile[rr][c4 + 1] = f2b(b2f(v.y) * s);
                tile[rr][c4 + 2] = f2b(b2f(v.z) * s);
                tile[rr][c4 + 3] = f2b(b2f(v.w) * s);
            }
            __syncthreads();
            #pragma unroll
            for (int i = 0; i < 4; i++) {
                int lin = i * 256 + t;
                int cc = lin >> 4, r4 = (lin & 15) << 2;
                ushort4 o;
                o.x = tile[r4][cc];     o.y = tile[r4 + 1][cc];
                o.z = tile[r4 + 2][cc]; o.w = tile[r4 + 3][cc];
                *(ushort4*)(YT + (long)(c0 + cc) * 8192 + r0 + r4) = o;
            }
        } else {
            float (*tf)[65] = (float(*)[65])smem;
            int j2 = job - 2048;
            int r0 = (j2 >> 4) * 64, c0 = (j2 & 15) * 64;
            #pragma unroll
            for (int i = 0; i < 4; i++) {
                int lin = i * 256 + t;
                int rr = lin >> 4, c4 = (lin & 15) << 2;
                float4 v = *(const float4*)(wgt + (long)(r0 + rr) * 1024 + c0 + c4);
                tf[rr][c4] = v.x; tf[rr][c4 + 1] = v.y; tf[rr][c4 + 2] = v.z; tf[rr][c4 + 3] = v.w;
            }
            __syncthreads();
            #pragma unroll
            for (int i = 0; i < 4; i++) {
                int lin = i * 256 + t;
                int cc = lin >> 4, r4 = (lin & 15) << 2;
                ushort4 o;
                o.x = f2b(tf[r4][cc]);     o.y = f2b(tf[r4 + 1][cc]);
                o.z = f2b(tf[r4 + 2][cc]); o.w = f2b(tf[r4 + 3][cc]);
                *(ushort4*)(Wt + (long)(c0 + cc) * 1024 + r0 + r4) = o;
            }
        }
    }
    gbar(cnt, gen);

    // ---- Phase C: G = Y^T·Y, sym tiles (72) x split-K 8 = 576 jobs ----
    if (bid < 576) {
        int tile = bid % 72, z = bid / 72;
        int id = tile, j = 0;
        while (true) {
            int c = (2 * j + 2 < 16) ? (2 * j + 2) : 16;
            if (id < c) break;
            id -= c; j++;
        }
        int tm = id, tn = j;
        const u16* Ap = YT + (long)tm * 64 * 8192 + (long)z * 1024;
        const u16* Bp = YT + (long)tn * 128 * 8192 + (long)z * 1024;
        gemm_body(Ap, Bp, As, Bs, nullptr, Gp + (long)z * MB, nullptr,
                  8192, 8192, 1024, tm * 64, tn * 128, 16);
    }
    gbar(cnt, gen);

    // ---- Phase D: Gb = bf16(sum Gp) with lower-triangle mirror (256 jobs) ----
    if (bid < 256) {
        float (*lt)[65] = (float(*)[65])smem;
        int ti = bid >> 4, tj = bid & 15;
        int r = t >> 4, c4 = (t & 15) << 2;
        int kept = (ti <= 2 * (tj >> 1) + 1);
        if (kept) {
            #pragma unroll
            for (int it = 0; it < 4; it++) {
                int row = 64 * ti + it * 16 + r;
                long idx = (long)row * 1024 + 64 * tj + c4;
                float s0 = 0, s1 = 0, s2 = 0, s3 = 0;
                for (int z = 0; z < 8; z++) {
                    ushort4 v = *(const ushort4*)(Gp + (long)z * MB + idx);
                    s0 += b2f(v.x); s1 += b2f(v.y); s2 += b2f(v.z); s3 += b2f(v.w);
                }
                ushort4 o; o.x = f2b(s0); o.y = f2b(s1); o.z = f2b(s2); o.w = f2b(s3);
                *(ushort4*)(Gb + idx) = o;
            }
        } else {
            #pragma unroll
            for (int it = 0; it < 4; it++) {
                int row = it * 16 + r;
                long idx = (long)(64 * tj + row) * 1024 + 64 * ti + c4;
                float s0 = 0, s1 = 0, s2 = 0, s3 = 0;
                for (int z = 0; z < 8; z++) {
                    ushort4 v = *(const ushort4*)(Gp + (long)z * MB + idx);
                    s0 += b2f(v.x); s1 += b2f(v.y); s2 += b2f(v.z); s3 += b2f(v.w);
                }
                lt[row][c4] = s0; lt[row][c4 + 1] = s1; lt[row][c4 + 2] = s2; lt[row][c4 + 3] = s3;
            }
            __syncthreads();
            #pragma unroll
            for (int it = 0; it < 4; it++) {
                int dr = it * 16 + r;
                ushort4 o;
                o.x = f2b(lt[c4 + 0][dr]); o.y = f2b(lt[c4 + 1][dr]);
                o.z = f2b(lt[c4 + 2][dr]); o.w = f2b(lt[c4 + 3][dr]);
                *(ushort4*)(Gb + (long)(64 * ti + dr) * 1024 + 64 * tj + c4) = o;
            }
        }
    }
    gbar(cnt, gen);

    // ---- Phase E: M^T = W^T·G, 128 tiles x split-K 4 = 512 jobs ----
    if (bid < 512) {
        int tile = bid % 128, z = bid / 128;
        int tm = tile / 8, tn = tile % 8;
        const u16* Ap = Wt + (long)tm * 64 * 1024 + (long)z * 256;
        const u16* Bp = Gb + (long)tn * 128 * 1024 + (long)z * 256;
        gemm_body(Ap, Bp, As, Bs, nullptr, Mp + (long)z * MB, nullptr,
                  1024, 1024, 1024, tm * 64, tn * 128, 4);
    }
    gbar(cnt, gen);

    // ---- Phase F: Mt = bf16(sum Mp) (1024 jobs x 1K elems) ----
    {
        long i = ((long)bid * 256 + t) * 4;
        float s0 = 0, s1 = 0, s2 = 0, s3 = 0;
        #pragma unroll
        for (int z = 0; z < 4; z++) {
            ushort4 v = *(const ushort4*)(Mp + (long)z * MB + i);
            s0 += b2f(v.x); s1 += b2f(v.y); s2 += b2f(v.z); s3 += b2f(v.w);
        }
        ushort4 o; o.x = f2b(s0); o.y = f2b(s1); o.z = f2b(s2); o.w = f2b(s3);
        *(ushort4*)(Mt + i) = o;
    }
    gbar(cnt, gen);

    // ---- Phase G: out = diag(rnorm)·xb·M (128x8 tiles = 1024 jobs) ----
    {
        int tm = bid / 8, tn = bid % 8;
        const u16* Ap = xb + (long)tm * 64 * 1024;
        const u16* Bp = Mt + (long)tn * 128 * 1024;
        gemm_body(Ap, Bp, As, Bs, out, nullptr, rnorm,
                  1024, 1024, 1024, tm * 64, tn * 128, 16);
    }
}

extern "C" void kernel_launch(void* const* d_in, const int* in_sizes, int n_in,
                              void* d_out, int out_size, void* d_ws, size_t ws_size,
                              hipStream_t stream) {
    const float* x = (const float*)d_in[0];
    const float* wgt = (const float*)d_in[1];
    float* out = (float*)d_out;
    char* ws = (char*)d_ws;

    // zero the grid-barrier state (cnt, gen)
    hipMemsetAsync(ws, 0, 4096, stream);
    fused_gcn<<<NB, 256, 0, stream>>>(x, wgt, out, ws);
}

// Round 8
// 670.672 us; speedup vs baseline: 1.8875x; 1.8875x over previous
//
#include <hip/hip_runtime.h>
#include <stdint.h>

typedef unsigned short u16;
typedef unsigned int u32;
typedef __attribute__((ext_vector_type(8))) short short8;
typedef __attribute__((ext_vector_type(4))) float floatx4;

#define NB 1024  // grid size; co-resident at 4 blocks/CU x 256 CUs (proven by R7)

__device__ __forceinline__ u16 f2b(float f) {
    u32 u = __builtin_bit_cast(u32, f);
    return (u16)((u + 0x7fffu + ((u >> 16) & 1u)) >> 16);
}
__device__ __forceinline__ float b2f(u16 b) {
    u32 u = ((u32)b) << 16;
    return __builtin_bit_cast(float, u);
}
__device__ __forceinline__ void gld16(const void* g, void* l) {
    __builtin_amdgcn_global_load_lds(
        (const __attribute__((address_space(1))) u32*)g,
        (__attribute__((address_space(3))) u32*)l, 16, 0, 0);
}

// Device-scope grid barrier. KEY: the spin uses RELAXED agent loads (go to the
// coherence point, NO L2 invalidate). Exactly one ACQUIRE per block per barrier
// after the flip; RELEASE on arrival (L2 writeback of this block's phase output).
// R7's acquire-in-spin-loop variant invalidated L2 continuously -> 7x slowdown.
__device__ __forceinline__ void gbar(u32* cnt, u32* gen) {
    __syncthreads();
    if (threadIdx.x == 0) {
        u32 g = __hip_atomic_load(gen, __ATOMIC_RELAXED, __HIP_MEMORY_SCOPE_AGENT);
        u32 a = __hip_atomic_fetch_add(cnt, 1u, __ATOMIC_RELEASE, __HIP_MEMORY_SCOPE_AGENT);
        if (a == NB - 1u) {
            __hip_atomic_store(cnt, 0u, __ATOMIC_RELAXED, __HIP_MEMORY_SCOPE_AGENT);
            __hip_atomic_store(gen, g + 1u, __ATOMIC_RELEASE, __HIP_MEMORY_SCOPE_AGENT);
        } else {
            while (__hip_atomic_load(gen, __ATOMIC_RELAXED, __HIP_MEMORY_SCOPE_AGENT) == g)
                __builtin_amdgcn_s_sleep(4);
        }
        (void)__hip_atomic_load(gen, __ATOMIC_ACQUIRE, __HIP_MEMORY_SCOPE_AGENT);
    }
    __syncthreads();
}

// 64(M)x128(N) tile GEMM body, BK=64, 256 thr (2x2 waves of 32x64).
// XOR-swizzled LDS, conflict-free ds_read_b128. Ap/Bp pre-offset to tile+kOff.
// Cp!=null -> bf16 store; else fp32 C with rowscale.
__device__ __forceinline__ void gemm_body(
    const u16* Ap, const u16* Bp, u16* As, u16* Bs,
    float* C, u16* Cp, const float* __restrict__ rowscale,
    int lda, int ldb, int ldc, int m0base, int n0base, int kIters) {
    int t = threadIdx.x;
    int lane = t & 63, w = t >> 6;
    int wm = (w & 1) * 32, wn = (w >> 1) * 64;
    int r16 = lane & 15, q = lane >> 4;

    int acl[2], bcl[4];
    #pragma unroll
    for (int j = 0; j < 2; j++) acl[j] = (w * 2 + j) * 64 + lane;
    #pragma unroll
    for (int j = 0; j < 4; j++) bcl[j] = (w * 4 + j) * 64 + lane;

    floatx4 acc[2][4];
    #pragma unroll
    for (int i = 0; i < 2; i++)
        #pragma unroll
        for (int j = 0; j < 4; j++) acc[i][j] = (floatx4){0.f, 0.f, 0.f, 0.f};

    for (int kt = 0; kt < kIters; kt++) {
        long kk = (long)kt * 64;
        #pragma unroll
        for (int j = 0; j < 2; j++) {
            int cl = acl[j], row = cl >> 3, cg = (cl & 7) ^ (row & 7);
            gld16(Ap + (long)row * lda + kk + cg * 8, (void*)&As[cl * 8]);
        }
        #pragma unroll
        for (int j = 0; j < 4; j++) {
            int cl = bcl[j], row = cl >> 3, cg = (cl & 7) ^ (row & 7);
            gld16(Bp + (long)row * ldb + kk + cg * 8, (void*)&Bs[cl * 8]);
        }
        __syncthreads();
        #pragma unroll
        for (int ks = 0; ks < 2; ks++) {
            short8 a[2], b[4];
            #pragma unroll
            for (int i = 0; i < 2; i++) {
                int rr = wm + i * 16 + r16;
                int cc = (ks * 4 + q) ^ (rr & 7);
                a[i] = *(const short8*)&As[rr * 64 + cc * 8];
            }
            #pragma unroll
            for (int j = 0; j < 4; j++) {
                int rr = wn + j * 16 + r16;
                int cc = (ks * 4 + q) ^ (rr & 7);
                b[j] = *(const short8*)&Bs[rr * 64 + cc * 8];
            }
            #pragma unroll
            for (int i = 0; i < 2; i++)
                #pragma unroll
                for (int j = 0; j < 4; j++)
                    acc[i][j] = __builtin_amdgcn_mfma_f32_16x16x32_bf16(a[i], b[j], acc[i][j], 0, 0, 0);
        }
        __syncthreads();
    }

    int m0 = m0base + wm, n0 = n0base + wn;
    #pragma unroll
    for (int i = 0; i < 2; i++) {
        int mm = m0 + i * 16 + q * 4;
        float rs[4];
        #pragma unroll
        for (int r = 0; r < 4; r++) rs[r] = (rowscale != nullptr) ? rowscale[mm + r] : 1.0f;
        #pragma unroll
        for (int j = 0; j < 4; j++) {
            int nn = n0 + j * 16 + r16;
            #pragma unroll
            for (int r = 0; r < 4; r++) {
                long idx = (long)(mm + r) * ldc + nn;
                if (Cp != nullptr) Cp[idx] = f2b(acc[i][j][r]);
                else               C[idx] = acc[i][j][r] * rs[r];
            }
        }
    }
}

__global__ __launch_bounds__(256, 4) void fused_gcn(
    const float* __restrict__ x, const float* __restrict__ wgt,
    float* __restrict__ out, char* __restrict__ ws) {
    __shared__ __align__(16) char smem[24576];
    u16* As = (u16*)smem;
    u16* Bs = (u16*)(smem + 8192);

    u32* cnt = (u32*)ws;
    u32* gen = (u32*)(ws + 64);
    const size_t MB = 1048576;
    float* rnorm  = (float*)(ws + 4096);
    float* srnorm = (float*)(ws + 36864);
    char*  base   = ws + 65536 + 4096;
    u16* xb = (u16*)base;                  // 16 MB bf16(x) [8192][1024]
    u16* YT = (u16*)(base + 16 * MB);      // 16 MB Y^T [1024][8192]
    u16* Wt = (u16*)(base + 32 * MB);      //  2 MB W^T
    u16* Gb = (u16*)(base + 34 * MB);      //  2 MB G bf16
    u16* Mt = (u16*)(base + 36 * MB);      //  2 MB M^T bf16
    u16* Gp = (u16*)(base + 38 * MB);      // 16 MB 8 bf16 G-partial slabs
    u16* Mp = (u16*)(base + 54 * MB);      //  8 MB 4 bf16 M-partial slabs

    int bid = blockIdx.x;
    int t = threadIdx.x;
    int lane = t & 63, w = t >> 6;

    // ---- Phase A: row norms + xb = bf16(x). 8 rows/block, 2 rows/wave ----
    #pragma unroll
    for (int rr = 0; rr < 2; rr++) {
        int row = bid * 8 + w * 2 + rr;
        const float4* xr = (const float4*)(x + (long)row * 1024);
        float4 v[4];
        float ss = 0.f;
        #pragma unroll
        for (int j = 0; j < 4; j++) {
            v[j] = xr[lane + 64 * j];
            ss += v[j].x * v[j].x + v[j].y * v[j].y + v[j].z * v[j].z + v[j].w * v[j].w;
        }
        #pragma unroll
        for (int off = 1; off < 64; off <<= 1) ss += __shfl_xor(ss, off);
        float r = 1.0f / fmaxf(sqrtf(ss), 1e-12f);
        if (lane == 0) { rnorm[row] = r; srnorm[row] = sqrtf(r); }
        #pragma unroll
        for (int j = 0; j < 4; j++) {
            ushort4 o;
            o.x = f2b(v[j].x); o.y = f2b(v[j].y); o.z = f2b(v[j].z); o.w = f2b(v[j].w);
            *(ushort4*)(xb + (long)row * 1024 + (lane + 64 * j) * 4) = o;
        }
    }
    gbar(cnt, gen);

    // ---- Phase B: YT from xb (jobs 0..2047) + Wt from wgt (jobs 2048..2303) ----
    for (int job = bid; job < 2304; job += NB) {
        __syncthreads();  // protect smem reuse
        if (job < 2048) {
            u16 (*tile)[72] = (u16(*)[72])smem;
            float* rb = (float*)(smem + 64 * 72 * 2);
            int r0 = (job >> 4) * 64, c0 = (job & 15) * 64;
            if (t < 64) rb[t] = srnorm[r0 + t];
            __syncthreads();
            #pragma unroll
            for (int i = 0; i < 4; i++) {
                int lin = i * 256 + t;
                int rr = lin >> 4, c4 = (lin & 15) << 2;
                ushort4 v = *(const ushort4*)(xb + (long)(r0 + rr) * 1024 + c0 + c4);
                float s = rb[rr];
                tile[rr][c4]     = f2b(b2f(v.x) * s);
                tile[rr][c4 + 1] = f2b(b2f(v.y) * s);
                tile[rr][c4 + 2] = f2b(b2f(v.z) * s);
                tile[rr][c4 + 3] = f2b(b2f(v.w) * s);
            }
            __syncthreads();
            #pragma unroll
            for (int i = 0; i < 4; i++) {
                int lin = i * 256 + t;
                int cc = lin >> 4, r4 = (lin & 15) << 2;
                ushort4 o;
                o.x = tile[r4][cc];     o.y = tile[r4 + 1][cc];
                o.z = tile[r4 + 2][cc]; o.w = tile[r4 + 3][cc];
                *(ushort4*)(YT + (long)(c0 + cc) * 8192 + r0 + r4) = o;
            }
        } else {
            float (*tf)[65] = (float(*)[65])smem;
            int j2 = job - 2048;
            int r0 = (j2 >> 4) * 64, c0 = (j2 & 15) * 64;
            #pragma unroll
            for (int i = 0; i < 4; i++) {
                int lin = i * 256 + t;
                int rr = lin >> 4, c4 = (lin & 15) << 2;
                float4 v = *(const float4*)(wgt + (long)(r0 + rr) * 1024 + c0 + c4);
                tf[rr][c4] = v.x; tf[rr][c4 + 1] = v.y; tf[rr][c4 + 2] = v.z; tf[rr][c4 + 3] = v.w;
            }
            __syncthreads();
            #pragma unroll
            for (int i = 0; i < 4; i++) {
                int lin = i * 256 + t;
                int cc = lin >> 4, r4 = (lin & 15) << 2;
                ushort4 o;
                o.x = f2b(tf[r4][cc]);     o.y = f2b(tf[r4 + 1][cc]);
                o.z = f2b(tf[r4 + 2][cc]); o.w = f2b(tf[r4 + 3][cc]);
                *(ushort4*)(Wt + (long)(c0 + cc) * 1024 + r0 + r4) = o;
            }
        }
    }
    gbar(cnt, gen);

    // ---- Phase C: G = Y^T·Y, sym tiles (72) x split-K 8 = 576 jobs ----
    if (bid < 576) {
        int tile = bid % 72, z = bid / 72;
        int id = tile, j = 0;
        while (true) {
            int c = (2 * j + 2 < 16) ? (2 * j + 2) : 16;
            if (id < c) break;
            id -= c; j++;
        }
        int tm = id, tn = j;
        const u16* Ap = YT + (long)tm * 64 * 8192 + (long)z * 1024;
        const u16* Bp = YT + (long)tn * 128 * 8192 + (long)z * 1024;
        gemm_body(Ap, Bp, As, Bs, nullptr, Gp + (long)z * MB, nullptr,
                  8192, 8192, 1024, tm * 64, tn * 128, 16);
    }
    gbar(cnt, gen);

    // ---- Phase D: Gb = bf16(sum Gp) with lower-triangle mirror (256 jobs) ----
    if (bid < 256) {
        float (*lt)[65] = (float(*)[65])smem;
        int ti = bid >> 4, tj = bid & 15;
        int r = t >> 4, c4 = (t & 15) << 2;
        int kept = (ti <= 2 * (tj >> 1) + 1);
        if (kept) {
            #pragma unroll
            for (int it = 0; it < 4; it++) {
                int row = 64 * ti + it * 16 + r;
                long idx = (long)row * 1024 + 64 * tj + c4;
                float s0 = 0, s1 = 0, s2 = 0, s3 = 0;
                for (int z = 0; z < 8; z++) {
                    ushort4 v = *(const ushort4*)(Gp + (long)z * MB + idx);
                    s0 += b2f(v.x); s1 += b2f(v.y); s2 += b2f(v.z); s3 += b2f(v.w);
                }
                ushort4 o; o.x = f2b(s0); o.y = f2b(s1); o.z = f2b(s2); o.w = f2b(s3);
                *(ushort4*)(Gb + idx) = o;
            }
        } else {
            #pragma unroll
            for (int it = 0; it < 4; it++) {
                int row = it * 16 + r;
                long idx = (long)(64 * tj + row) * 1024 + 64 * ti + c4;
                float s0 = 0, s1 = 0, s2 = 0, s3 = 0;
                for (int z = 0; z < 8; z++) {
                    ushort4 v = *(const ushort4*)(Gp + (long)z * MB + idx);
                    s0 += b2f(v.x); s1 += b2f(v.y); s2 += b2f(v.z); s3 += b2f(v.w);
                }
                lt[row][c4] = s0; lt[row][c4 + 1] = s1; lt[row][c4 + 2] = s2; lt[row][c4 + 3] = s3;
            }
            __syncthreads();
            #pragma unroll
            for (int it = 0; it < 4; it++) {
                int dr = it * 16 + r;
                ushort4 o;
                o.x = f2b(lt[c4 + 0][dr]); o.y = f2b(lt[c4 + 1][dr]);
                o.z = f2b(lt[c4 + 2][dr]); o.w = f2b(lt[c4 + 3][dr]);
                *(ushort4*)(Gb + (long)(64 * ti + dr) * 1024 + 64 * tj + c4) = o;
            }
        }
    }
    gbar(cnt, gen);

    // ---- Phase E: M^T = W^T·G, 128 tiles x split-K 4 = 512 jobs ----
    if (bid < 512) {
        int tile = bid % 128, z = bid / 128;
        int tm = tile / 8, tn = tile % 8;
        const u16* Ap = Wt + (long)tm * 64 * 1024 + (long)z * 256;
        const u16* Bp = Gb + (long)tn * 128 * 1024 + (long)z * 256;
        gemm_body(Ap, Bp, As, Bs, nullptr, Mp + (long)z * MB, nullptr,
                  1024, 1024, 1024, tm * 64, tn * 128, 4);
    }
    gbar(cnt, gen);

    // ---- Phase F: Mt = bf16(sum Mp) (1024 jobs x 1K elems) ----
    {
        long i = ((long)bid * 256 + t) * 4;
        float s0 = 0, s1 = 0, s2 = 0, s3 = 0;
        #pragma unroll
        for (int z = 0; z < 4; z++) {
            ushort4 v = *(const ushort4*)(Mp + (long)z * MB + i);
            s0 += b2f(v.x); s1 += b2f(v.y); s2 += b2f(v.z); s3 += b2f(v.w);
        }
        ushort4 o; o.x = f2b(s0); o.y = f2b(s1); o.z = f2b(s2); o.w = f2b(s3);
        *(ushort4*)(Mt + i) = o;
    }
    gbar(cnt, gen);

    // ---- Phase G: out = diag(rnorm)·xb·M (128x8 tiles = 1024 jobs) ----
    {
        int tm = bid / 8, tn = bid % 8;
        const u16* Ap = xb + (long)tm * 64 * 1024;
        const u16* Bp = Mt + (long)tn * 128 * 1024;
        gemm_body(Ap, Bp, As, Bs, out, nullptr, rnorm,
                  1024, 1024, 1024, tm * 64, tn * 128, 16);
    }
}

extern "C" void kernel_launch(void* const* d_in, const int* in_sizes, int n_in,
                              void* d_out, int out_size, void* d_ws, size_t ws_size,
                              hipStream_t stream) {
    const float* x = (const float*)d_in[0];
    const float* wgt = (const float*)d_in[1];
    float* out = (float*)d_out;
    char* ws = (char*)d_ws;

    // zero the grid-barrier state (cnt, gen)
    hipMemsetAsync(ws, 0, 4096, stream);
    fused_gcn<<<NB, 256, 0, stream>>>(x, wgt, out, ws);
}